// Round 14
// baseline (392.095 us; speedup 1.0000x reference)
//
#include <hip/hip_runtime.h>
#include <hip/hip_bf16.h>
#include <hip/hip_cooperative_groups.h>
#include <math.h>

#define SEQ 2048
#define DM 2048
#define NH 16
#define HD 128
#define QKV_N 6144

typedef __bf16 bf16;
typedef __bf16 bf16x8 __attribute__((ext_vector_type(8)));
typedef __bf16 bf16x4v __attribute__((ext_vector_type(4)));
typedef __bf16 bf16x2v __attribute__((ext_vector_type(2)));
typedef float f32x4 __attribute__((ext_vector_type(4)));

// 64-elem-row swizzle (8 chunk slots, 128B row = full bank revolution)
__device__ inline int sw_idx64(int row, int chunk) {
    return (row * 8 + (chunk ^ (row & 7))) * 8;
}
// 128-elem-row swizzle (16 chunk slots, 256B row)
__device__ inline int sw_idx128(int row, int chunk) {
    return (row * 16 + (chunk ^ (row & 15))) * 8;
}
// 32-elem-row swizzle (4 chunk slots, 64B row) -- per-wave P slices
__device__ inline int sw_idx32(int row, int chunk) {
    return (row * 4 + (chunk ^ (row & 3))) * 8;
}

__device__ inline void async16(const void* g, void* l) {
    __builtin_amdgcn_global_load_lds((const __attribute__((address_space(1))) void*)g,
                                     (__attribute__((address_space(3))) void*)l, 16, 0, 0);
}

// ---- weight transposes (z<4, 64x64 tiles, float4 loads) + x convert (z=4) --
__global__ __launch_bounds__(256) void k_prep(const float* __restrict__ wq,
                                              const float* __restrict__ wk,
                                              const float* __restrict__ wv,
                                              const float* __restrict__ wo,
                                              bf16* __restrict__ wT, bf16* __restrict__ woT,
                                              const float* __restrict__ x,
                                              bf16* __restrict__ xb) {
    const int z = blockIdx.z;
    const int t = threadIdx.x;
    if (z == 4) {                                    // x convert: 1M float4s
        int bid = blockIdx.y * 32 + blockIdx.x;      // 0..1023
#pragma unroll
        for (int j = 0; j < 4; ++j) {
            int i = bid * 1024 + j * 256 + t;
            float4 v = ((const float4*)x)[i];
            bf16x4v o;
            o.x = (bf16)v.x; o.y = (bf16)v.y; o.z = (bf16)v.z; o.w = (bf16)v.w;
            ((bf16x4v*)xb)[i] = o;
        }
        return;
    }
    __shared__ bf16 tile[64][66];
    const float* src = (z == 0) ? wq : (z == 1) ? wk : (z == 2) ? wv : wo;
    bf16* dst = (z < 3) ? (wT + (size_t)z * DM * DM) : woT;
    const int bx = blockIdx.x * 64, by = blockIdx.y * 64;
#pragma unroll
    for (int j = 0; j < 4; ++j) {
        int idx = j * 256 + t;                       // 0..1023
        int r = idx >> 4, cg = idx & 15;
        float4 v = *(const float4*)&src[(size_t)(by + r) * DM + bx + cg * 4];
        bf16x4v o;
        o.x = (bf16)v.x; o.y = (bf16)v.y; o.z = (bf16)v.z; o.w = (bf16)v.w;
        *(bf16x4v*)&tile[r][cg * 4] = o;
    }
    __syncthreads();
#pragma unroll
    for (int j = 0; j < 4; ++j) {
        int idx = j * 256 + t;
        int r = idx >> 4, cg = idx & 15;
        bf16x4v o;
        o.x = tile[cg * 4 + 0][r];
        o.y = tile[cg * 4 + 1][r];
        o.z = tile[cg * 4 + 2][r];
        o.w = tile[cg * 4 + 3][r];
        *(bf16x4v*)&dst[(size_t)(bx + r) * DM + by + cg * 4] = o;
    }
}

// ---- shared 128xBN GEMM body: C[.][N] = A[M][K] * Bt[N][K]^T --------------
template <typename OutT, int BN>
__device__ __forceinline__ void gemm_body(const bf16* __restrict__ A,
                                          const bf16* __restrict__ Bt,
                                          OutT* __restrict__ C,
                                          int N, int K, size_t bm, size_t bn,
                                          bf16* As, bf16* Bs) {
    constexpr int NI = BN / 32;
    const int t = threadIdx.x;
    const int lane = t & 63;
    const int w = t >> 6;
    const int wr = (w >> 1) * 64, wc = (w & 1) * (BN / 2);
    const int l15 = lane & 15, quad = lane >> 4;
    f32x4 acc[4][NI];
#pragma unroll
    for (int i = 0; i < 4; ++i)
#pragma unroll
        for (int j = 0; j < NI; ++j) acc[i][j] = (f32x4){0.f, 0.f, 0.f, 0.f};

    for (int kt = 0; kt < K; kt += 64) {
#pragma unroll
        for (int j = 0; j < 4; ++j) {
            int c = j * 256 + t;
            int row = c >> 3, g = ((c & 7) ^ (row & 7)) * 8;
            async16(&A[(bm + row) * K + kt + g], &As[c * 8]);
        }
#pragma unroll
        for (int j = 0; j < NI; ++j) {
            int c = j * 256 + t;
            int row = c >> 3, g = ((c & 7) ^ (row & 7)) * 8;
            async16(&Bt[(bn + row) * K + kt + g], &Bs[c * 8]);
        }
        __syncthreads();
#pragma unroll
        for (int kh = 0; kh < 2; ++kh) {
            bf16x8 af[4], bfm[NI];
#pragma unroll
            for (int mi = 0; mi < 4; ++mi)
                af[mi] = *(const bf16x8*)&As[sw_idx64(wr + mi * 16 + l15, kh * 4 + quad)];
#pragma unroll
            for (int ni = 0; ni < NI; ++ni)
                bfm[ni] = *(const bf16x8*)&Bs[sw_idx64(wc + ni * 16 + l15, kh * 4 + quad)];
#pragma unroll
            for (int mi = 0; mi < 4; ++mi)
#pragma unroll
                for (int ni = 0; ni < NI; ++ni)
                    acc[mi][ni] = __builtin_amdgcn_mfma_f32_16x16x32_bf16(
                        af[mi], bfm[ni], acc[mi][ni], 0, 0, 0);
        }
        __syncthreads();
    }
#pragma unroll
    for (int mi = 0; mi < 4; ++mi)
#pragma unroll
        for (int ni = 0; ni < NI; ++ni)
#pragma unroll
            for (int r = 0; r < 4; ++r) {
                size_t row = bm + wr + mi * 16 + quad * 4 + r;
                size_t col = bn + wc + ni * 16 + l15;
                C[row * (size_t)N + col] = (OutT)acc[mi][ni][r];
            }
}

template <typename OutT, int BN>
__global__ __launch_bounds__(256) void k_gemm_bt(const bf16* __restrict__ A,
                                                 const bf16* __restrict__ Bt,
                                                 OutT* __restrict__ C,
                                                 int M, int N, int K) {
    __shared__ bf16 As[128 * 64];
    __shared__ bf16 Bs[BN * 64];
    size_t bm = (size_t)blockIdx.y * 128, bn = (size_t)blockIdx.x * BN;
    gemm_body<OutT, BN>(A, Bt, C, N, K, bm, bn, As, Bs);
}

// ============================================================================
// k_mega: cooperative fusion of {K-rope + V-transpose} -> flash -> out-proj.
// Grid 512 x 512 threads, 2 blocks/CU co-resident (LDS 72KB, VGPR<=128 via
// launch_bounds(512,4)) -> cooperative grid.sync() is valid.  Eliminates 2
// kernel-launch gaps (hypothesis: ~17-20us each).
// ============================================================================
__global__ __launch_bounds__(512, 4) void k_mega(bf16* __restrict__ qkv,
                                                 bf16* __restrict__ vT,
                                                 const float* __restrict__ cosT,
                                                 const float* __restrict__ sinT,
                                                 bf16* __restrict__ xb,
                                                 const bf16* __restrict__ woT,
                                                 float* __restrict__ out) {
    __shared__ __align__(16) char smem[73728];       // 72KB union
    const int t = threadIdx.x;
    const int b = blockIdx.x;

    // ---------------- Phase A: K-RoPE (in-place) + V transpose --------------
    {
        // K RoPE: 512K groups of 8 channels; 2 per thread, coalesced
#pragma unroll
        for (int j = 0; j < 2; ++j) {
            int g = b * 1024 + j * 512 + t;          // 0..524287
            int s = g >> 8;
            int cg = g & 255;
            int h = cg >> 4, w8 = cg & 15;
            size_t base = (size_t)s * QKV_N + DM + h * HD + w8 * 8;
            float4 cv = *(const float4*)&cosT[s * 64 + w8 * 4];
            float4 sv = *(const float4*)&sinT[s * 64 + w8 * 4];
            float cc[4] = {cv.x, cv.y, cv.z, cv.w};
            float ss[4] = {sv.x, sv.y, sv.z, sv.w};
            bf16x8 k = *(bf16x8*)&qkv[base];
            bf16x8 o;
#pragma unroll
            for (int p = 0; p < 4; ++p) {
                float re = (float)k[2 * p], im = (float)k[2 * p + 1];
                o[2 * p]     = (bf16)(re * cc[p] - im * ss[p]);
                o[2 * p + 1] = (bf16)(re * ss[p] + im * cc[p]);
            }
            *(bf16x8*)&qkv[base] = o;
        }
        // V transpose: 1024 64x64 tiles; 2 per block (one per 256-thr half)
        const int half = t >> 8, tt = t & 255;
        bf16* tl = (bf16*)(smem + half * 8448);      // [64][66]
        const int tile = b * 2 + half;               // 0..1023
        const int bx = (tile & 31) * 64, by = (tile >> 5) * 64;
#pragma unroll
        for (int j = 0; j < 4; ++j) {
            int idx = j * 256 + tt;
            int r = idx >> 4, cg = idx & 15;
            *(bf16x4v*)&tl[r * 66 + cg * 4] =
                *(const bf16x4v*)&qkv[(size_t)(by + r) * QKV_N + 2 * DM + bx + cg * 4];
        }
        __syncthreads();
#pragma unroll
        for (int j = 0; j < 4; ++j) {
            int idx = j * 256 + tt;
            int r = idx >> 4, cg = idx & 15;
            bf16x4v o;
            o.x = tl[(cg * 4 + 0) * 66 + r];
            o.y = tl[(cg * 4 + 1) * 66 + r];
            o.z = tl[(cg * 4 + 2) * 66 + r];
            o.w = tl[(cg * 4 + 3) * 66 + r];
            *(bf16x4v*)&vT[(size_t)(bx + r) * SEQ + by + cg * 4] = o;
        }
    }
    cooperative_groups::this_grid().sync();

    // ---------------- Phase B: causal flash attention (r13 body) ------------
    {
        bf16* KsB = (bf16*)smem;                     // [2][64*128] 32KB
        bf16* VsB = (bf16*)(smem + 32768);           // [2][128*64] 32KB
        bf16* PlB = (bf16*)(smem + 65536);           // [8][16*32]   8KB
        const int lane = t & 63;
        const int w = t >> 6;                        // 0..7
        const int wl = w & 3;                        // q-strip
        const int g = w >> 2;                        // key-half 0/1
        const int l15 = lane & 15, quad = lane >> 4;
        const int hc = b & 15;
        const int h = (hc & 7) * 2 + (hc >> 3);
        const int qb = (b < 256) ? (31 - (b >> 4)) : ((b >> 4) - 16);
        const int q0w = qb * 64 + wl * 16;
        const float sc2 = 0.08838834764831845f * 1.4426950408889634f;

        const size_t qrow = (size_t)(q0w + l15) * QKV_N + h * HD;
        bf16x8 aq[4];
#pragma unroll
        for (int u = 0; u < 4; ++u)
            aq[u] = *(const bf16x8*)&qkv[qrow + u * 32 + quad * 8];
#pragma unroll
        for (int u = 0; u < 4; ++u) {
            float4 cv = *(const float4*)&cosT[(q0w + l15) * 64 + u * 16 + quad * 4];
            float4 sv = *(const float4*)&sinT[(q0w + l15) * 64 + u * 16 + quad * 4];
            float cc[4] = {cv.x, cv.y, cv.z, cv.w};
            float ss[4] = {sv.x, sv.y, sv.z, sv.w};
            bf16x8 q = aq[u], rq;
#pragma unroll
            for (int pp = 0; pp < 4; ++pp) {
                float re = (float)q[2 * pp], im = (float)q[2 * pp + 1];
                rq[2 * pp]     = (bf16)(re * cc[pp] - im * ss[pp]);
                rq[2 * pp + 1] = (bf16)(re * ss[pp] + im * cc[pp]);
            }
            aq[u] = rq;
        }

        f32x4 o[8];
#pragma unroll
        for (int c = 0; c < 8; ++c) o[c] = (f32x4){0.f, 0.f, 0.f, 0.f};
        float l_r[4] = {0.f, 0.f, 0.f, 0.f};

        int krow[2], kg[2], vrow[2], vg[2];
#pragma unroll
        for (int j = 0; j < 2; ++j) {
            int c2 = j * 512 + t;
            krow[j] = c2 >> 4; kg[j] = ((c2 & 15) ^ (krow[j] & 15)) * 8;
            vrow[j] = c2 >> 3; vg[j] = ((c2 & 7) ^ (vrow[j] & 7)) * 8;
        }
        auto stage = [&](int buf, int kt2) {
            const int kb2 = kt2 * 64;
#pragma unroll
            for (int j = 0; j < 2; ++j)
                async16(&qkv[(size_t)(kb2 + krow[j]) * QKV_N + DM + h * HD + kg[j]],
                        &KsB[buf * 8192 + (j * 512 + t) * 8]);
#pragma unroll
            for (int j = 0; j < 2; ++j)
                async16(&vT[(size_t)(h * HD + vrow[j]) * SEQ + kb2 + vg[j]],
                        &VsB[buf * 8192 + (j * 512 + t) * 8]);
        };

        const int nT = qb + 1;
        stage(0, 0);
        for (int kt = 0; kt < nT; ++kt) {
            const int cb = kt & 1;
            const int kbase = kt * 64;
            const bool pre = (kt + 1 < nT);
            if (pre) {
                stage(cb ^ 1, kt + 1);
                asm volatile("s_waitcnt vmcnt(6)" ::: "memory");
            } else {
                asm volatile("s_waitcnt vmcnt(2)" ::: "memory");
            }
            __builtin_amdgcn_s_barrier();
            asm volatile("" ::: "memory");

            f32x4 s4[2];
            __builtin_amdgcn_s_setprio(1);
#pragma unroll
            for (int sl = 0; sl < 2; ++sl) {
                const int sub = 2 * g + sl;
                f32x4 z = (f32x4){0.f, 0.f, 0.f, 0.f};
#pragma unroll
                for (int u = 0; u < 4; ++u) {
                    bf16x8 kv = *(const bf16x8*)&KsB[cb * 8192 +
                                    sw_idx128(sub * 16 + l15, u * 4 + quad)];
                    z = __builtin_amdgcn_mfma_f32_16x16x32_bf16(aq[u], kv, z, 0, 0, 0);
                }
                s4[sl] = z;
            }
            __builtin_amdgcn_s_setprio(0);
            const bool masked = (kt == qb);
#pragma unroll
            for (int sl = 0; sl < 2; ++sl) {
                const int sub = 2 * g + sl;
#pragma unroll
                for (int r = 0; r < 4; ++r) {
                    float pv = __builtin_amdgcn_exp2f(s4[sl][r] * sc2);
                    if (masked)
                        pv = (kbase + sub * 16 + l15 <= q0w + quad * 4 + r) ? pv : 0.f;
                    l_r[r] += pv;
                    int rowp = quad * 4 + r;
                    int lc = sl * 16 + l15;
                    PlB[w * 512 + (rowp * 4 + ((lc >> 3) ^ (rowp & 3))) * 8 + (lc & 7)] =
                        (bf16)pv;
                }
            }
            if (pre) asm volatile("s_waitcnt vmcnt(4)" ::: "memory");
            else     asm volatile("s_waitcnt vmcnt(0)" ::: "memory");
            __builtin_amdgcn_s_barrier();
            __asm__ __volatile__("s_waitcnt lgkmcnt(0)" ::: "memory");
            bf16x8 pf = *(const bf16x8*)&PlB[w * 512 + sw_idx32(l15, quad)];
            __builtin_amdgcn_s_setprio(1);
#pragma unroll
            for (int c = 0; c < 8; ++c) {
                bf16x8 vb = *(const bf16x8*)&VsB[cb * 8192 +
                                sw_idx64(c * 16 + l15, g * 4 + quad)];
                o[c] = __builtin_amdgcn_mfma_f32_16x16x32_bf16(pf, vb, o[c], 0, 0, 0);
            }
            __builtin_amdgcn_s_setprio(0);
            asm volatile("" ::: "memory");
            __builtin_amdgcn_s_barrier();
            asm volatile("" ::: "memory");
        }

        __syncthreads();
        float* oxch = (float*)smem;                  // 32KB
        float* lxch = (float*)(smem + 65536);        // 4KB
        const int tp = t & 255;
        if (g == 1) {
#pragma unroll
            for (int c = 0; c < 8; ++c)
                *(f32x4*)&oxch[tp * 32 + c * 4] = o[c];
#pragma unroll
            for (int r = 0; r < 4; ++r) lxch[tp * 4 + r] = l_r[r];
        }
        __syncthreads();
        if (g == 0) {
#pragma unroll
            for (int c = 0; c < 8; ++c) {
                f32x4 v = *(const f32x4*)&oxch[tp * 32 + c * 4];
                o[c] += v;
            }
#pragma unroll
            for (int r = 0; r < 4; ++r) l_r[r] += lxch[tp * 4 + r];
            float rl[4];
#pragma unroll
            for (int r = 0; r < 4; ++r) {
                float l = l_r[r];
                l += __shfl_xor(l, 1, 16);
                l += __shfl_xor(l, 2, 16);
                l += __shfl_xor(l, 4, 16);
                l += __shfl_xor(l, 8, 16);
                rl[r] = 1.0f / l;
            }
#pragma unroll
            for (int c = 0; c < 8; ++c)
#pragma unroll
                for (int r = 0; r < 4; ++r)
                    xb[(size_t)(q0w + quad * 4 + r) * DM + h * HD + c * 16 + l15] =
                        (bf16)(o[c][r] * rl[r]);
        }
    }
    cooperative_groups::this_grid().sync();

    // ---------------- Phase C: out-proj, 512 tiles of 128x64, full K --------
    {
        bf16* As = (bf16*)smem;                      // 128x64 = 16KB
        bf16* Bs = (bf16*)(smem + 32768);            //  64x64 =  8KB
        const int lane = t & 63;
        const int w2 = t >> 6;
        const int wrC = (w2 >> 1) * 32, wcC = (w2 & 1) * 32;
        const int l15 = lane & 15, quad = lane >> 4;
        const size_t bm2 = (size_t)(b >> 5) * 128;   // 16 M-tiles
        const size_t bn2 = (size_t)(b & 31) * 64;    // 32 N-tiles

        f32x4 acc[2][2];
#pragma unroll
        for (int i = 0; i < 2; ++i)
#pragma unroll
            for (int j = 0; j < 2; ++j) acc[i][j] = (f32x4){0.f, 0.f, 0.f, 0.f};

        for (int kt = 0; kt < DM; kt += 64) {
#pragma unroll
            for (int j = 0; j < 2; ++j) {            // A: 1024 chunks
                int c = j * 512 + t;
                int row = c >> 3, g8 = ((c & 7) ^ (row & 7)) * 8;
                async16(&xb[(bm2 + row) * DM + kt + g8], &As[c * 8]);
            }
            {                                        // B: 512 chunks
                int c = t;
                int row = c >> 3, g8 = ((c & 7) ^ (row & 7)) * 8;
                async16(&woT[(bn2 + row) * DM + kt + g8], &Bs[c * 8]);
            }
            __syncthreads();
#pragma unroll
            for (int kh = 0; kh < 2; ++kh) {
                bf16x8 af[2], bfm[2];
#pragma unroll
                for (int mi = 0; mi < 2; ++mi)
                    af[mi] = *(const bf16x8*)&As[sw_idx64(wrC + mi * 16 + l15, kh * 4 + quad)];
#pragma unroll
                for (int ni = 0; ni < 2; ++ni)
                    bfm[ni] = *(const bf16x8*)&Bs[sw_idx64(wcC + ni * 16 + l15, kh * 4 + quad)];
#pragma unroll
                for (int mi = 0; mi < 2; ++mi)
#pragma unroll
                    for (int ni = 0; ni < 2; ++ni)
                        acc[mi][ni] = __builtin_amdgcn_mfma_f32_16x16x32_bf16(
                            af[mi], bfm[ni], acc[mi][ni], 0, 0, 0);
            }
            __syncthreads();
        }
#pragma unroll
        for (int mi = 0; mi < 2; ++mi)
#pragma unroll
            for (int ni = 0; ni < 2; ++ni)
#pragma unroll
                for (int r = 0; r < 4; ++r) {
                    size_t row = bm2 + wrC + mi * 16 + quad * 4 + r;
                    size_t col = bn2 + wcC + ni * 16 + l15;
                    out[row * (size_t)DM + col] = acc[mi][ni][r];
                }
    }
}

// ---------------- standalone fallbacks (r13 versions) -----------------------
__global__ __launch_bounds__(256) void k_rope_vt(bf16* __restrict__ qkv,
                                                 const float* __restrict__ cosT,
                                                 const float* __restrict__ sinT,
                                                 bf16* __restrict__ vT) {
    const int t = threadIdx.x;
    if (blockIdx.x >= 1024) {
        int g = (blockIdx.x - 1024) * 256 + t;
        int s = g >> 8;
        int cg = g & 255;
        int h = cg >> 4, w8 = cg & 15;
        size_t base = (size_t)s * QKV_N + DM + h * HD + w8 * 8;
        float4 cv = *(const float4*)&cosT[s * 64 + w8 * 4];
        float4 sv = *(const float4*)&sinT[s * 64 + w8 * 4];
        float cc[4] = {cv.x, cv.y, cv.z, cv.w};
        float ss[4] = {sv.x, sv.y, sv.z, sv.w};
        bf16x8 k = *(bf16x8*)&qkv[base];
        bf16x8 o;
#pragma unroll
        for (int p = 0; p < 4; ++p) {
            float re = (float)k[2 * p], im = (float)k[2 * p + 1];
            o[2 * p]     = (bf16)(re * cc[p] - im * ss[p]);
            o[2 * p + 1] = (bf16)(re * ss[p] + im * cc[p]);
        }
        *(bf16x8*)&qkv[base] = o;
        return;
    }
    __shared__ bf16 tile[64][66];
    const int bx = (blockIdx.x & 31) * 64, by = (blockIdx.x >> 5) * 64;
#pragma unroll
    for (int j = 0; j < 4; ++j) {
        int idx = j * 256 + t;
        int r = idx >> 4, cg = idx & 15;
        *(bf16x4v*)&tile[r][cg * 4] =
            *(const bf16x4v*)&qkv[(size_t)(by + r) * QKV_N + 2 * DM + bx + cg * 4];
    }
    __syncthreads();
#pragma unroll
    for (int j = 0; j < 4; ++j) {
        int idx = j * 256 + t;
        int r = idx >> 4, cg = idx & 15;
        bf16x4v o;
        o.x = tile[cg * 4 + 0][r];
        o.y = tile[cg * 4 + 1][r];
        o.z = tile[cg * 4 + 2][r];
        o.w = tile[cg * 4 + 3][r];
        *(bf16x4v*)&vT[(size_t)(bx + r) * SEQ + by + cg * 4] = o;
    }
}

__global__ __launch_bounds__(512) void k_flash(const bf16* __restrict__ qkv,
                                               const bf16* __restrict__ vT,
                                               const float* __restrict__ cosT,
                                               const float* __restrict__ sinT,
                                               bf16* __restrict__ out) {
    __shared__ bf16 Ks[2][64 * 128];
    __shared__ bf16 Vs[2][128 * 64];
    __shared__ bf16 Pl[8][16 * 32];
    const int t = threadIdx.x;
    const int lane = t & 63;
    const int w = t >> 6;
    const int wl = w & 3;
    const int g = w >> 2;
    const int l15 = lane & 15, quad = lane >> 4;
    const int b = blockIdx.x;
    const int hc = b & 15;
    const int h = (hc & 7) * 2 + (hc >> 3);
    const int qb = (b < 256) ? (31 - (b >> 4)) : ((b >> 4) - 16);
    const int q0w = qb * 64 + wl * 16;
    const float sc2 = 0.08838834764831845f * 1.4426950408889634f;

    const size_t qrow = (size_t)(q0w + l15) * QKV_N + h * HD;
    bf16x8 aq[4];
#pragma unroll
    for (int u = 0; u < 4; ++u)
        aq[u] = *(const bf16x8*)&qkv[qrow + u * 32 + quad * 8];
#pragma unroll
    for (int u = 0; u < 4; ++u) {
        float4 cv = *(const float4*)&cosT[(q0w + l15) * 64 + u * 16 + quad * 4];
        float4 sv = *(const float4*)&sinT[(q0w + l15) * 64 + u * 16 + quad * 4];
        float cc[4] = {cv.x, cv.y, cv.z, cv.w};
        float ss[4] = {sv.x, sv.y, sv.z, sv.w};
        bf16x8 q = aq[u], rq;
#pragma unroll
        for (int pp = 0; pp < 4; ++pp) {
            float re = (float)q[2 * pp], im = (float)q[2 * pp + 1];
            rq[2 * pp]     = (bf16)(re * cc[pp] - im * ss[pp]);
            rq[2 * pp + 1] = (bf16)(re * ss[pp] + im * cc[pp]);
        }
        aq[u] = rq;
    }

    f32x4 o[8];
#pragma unroll
    for (int c = 0; c < 8; ++c) o[c] = (f32x4){0.f, 0.f, 0.f, 0.f};
    float l_r[4] = {0.f, 0.f, 0.f, 0.f};

    int krow[2], kg[2], vrow[2], vg[2];
#pragma unroll
    for (int j = 0; j < 2; ++j) {
        int c2 = j * 512 + t;
        krow[j] = c2 >> 4; kg[j] = ((c2 & 15) ^ (krow[j] & 15)) * 8;
        vrow[j] = c2 >> 3; vg[j] = ((c2 & 7) ^ (vrow[j] & 7)) * 8;
    }
    auto stage = [&](int buf, int kt2) {
        const int kb2 = kt2 * 64;
#pragma unroll
        for (int j = 0; j < 2; ++j)
            async16(&qkv[(size_t)(kb2 + krow[j]) * QKV_N + DM + h * HD + kg[j]],
                    &Ks[buf][(j * 512 + t) * 8]);
#pragma unroll
        for (int j = 0; j < 2; ++j)
            async16(&vT[(size_t)(h * HD + vrow[j]) * SEQ + kb2 + vg[j]],
                    &Vs[buf][(j * 512 + t) * 8]);
    };

    const int nT = qb + 1;
    stage(0, 0);
    for (int kt = 0; kt < nT; ++kt) {
        const int cb = kt & 1;
        const int kbase = kt * 64;
        const bool pre = (kt + 1 < nT);
        if (pre) {
            stage(cb ^ 1, kt + 1);
            asm volatile("s_waitcnt vmcnt(6)" ::: "memory");
        } else {
            asm volatile("s_waitcnt vmcnt(2)" ::: "memory");
        }
        __builtin_amdgcn_s_barrier();
        asm volatile("" ::: "memory");

        f32x4 s4[2];
        __builtin_amdgcn_s_setprio(1);
#pragma unroll
        for (int sl = 0; sl < 2; ++sl) {
            const int sub = 2 * g + sl;
            f32x4 z = (f32x4){0.f, 0.f, 0.f, 0.f};
#pragma unroll
            for (int u = 0; u < 4; ++u) {
                bf16x8 kv = *(const bf16x8*)&Ks[cb][sw_idx128(sub * 16 + l15, u * 4 + quad)];
                z = __builtin_amdgcn_mfma_f32_16x16x32_bf16(aq[u], kv, z, 0, 0, 0);
            }
            s4[sl] = z;
        }
        __builtin_amdgcn_s_setprio(0);
        const bool masked = (kt == qb);
#pragma unroll
        for (int sl = 0; sl < 2; ++sl) {
            const int sub = 2 * g + sl;
#pragma unroll
            for (int r = 0; r < 4; ++r) {
                float pv = __builtin_amdgcn_exp2f(s4[sl][r] * sc2);
                if (masked)
                    pv = (kbase + sub * 16 + l15 <= q0w + quad * 4 + r) ? pv : 0.f;
                l_r[r] += pv;
                int rowp = quad * 4 + r;
                int lc = sl * 16 + l15;
                Pl[w][(rowp * 4 + ((lc >> 3) ^ (rowp & 3))) * 8 + (lc & 7)] = (bf16)pv;
            }
        }
        if (pre) asm volatile("s_waitcnt vmcnt(4)" ::: "memory");
        else     asm volatile("s_waitcnt vmcnt(0)" ::: "memory");
        __builtin_amdgcn_s_barrier();
        __asm__ __volatile__("s_waitcnt lgkmcnt(0)" ::: "memory");
        bf16x8 pf = *(const bf16x8*)&Pl[w][sw_idx32(l15, quad)];
        __builtin_amdgcn_s_setprio(1);
#pragma unroll
        for (int c = 0; c < 8; ++c) {
            bf16x8 vb = *(const bf16x8*)&Vs[cb][sw_idx64(c * 16 + l15, g * 4 + quad)];
            o[c] = __builtin_amdgcn_mfma_f32_16x16x32_bf16(pf, vb, o[c], 0, 0, 0);
        }
        __builtin_amdgcn_s_setprio(0);
        asm volatile("" ::: "memory");
        __builtin_amdgcn_s_barrier();
        asm volatile("" ::: "memory");
    }

    __syncthreads();
    float* oxch = (float*)&Ks[0][0];
    float* lxch = (float*)&Pl[0][0];
    const int tp = t & 255;
    if (g == 1) {
#pragma unroll
        for (int c = 0; c < 8; ++c)
            *(f32x4*)&oxch[tp * 32 + c * 4] = o[c];
#pragma unroll
        for (int r = 0; r < 4; ++r) lxch[tp * 4 + r] = l_r[r];
    }
    __syncthreads();
    if (g == 0) {
#pragma unroll
        for (int c = 0; c < 8; ++c) {
            f32x4 v = *(const f32x4*)&oxch[tp * 32 + c * 4];
            o[c] += v;
        }
#pragma unroll
        for (int r = 0; r < 4; ++r) l_r[r] += lxch[tp * 4 + r];
        float rl[4];
#pragma unroll
        for (int r = 0; r < 4; ++r) {
            float l = l_r[r];
            l += __shfl_xor(l, 1, 16);
            l += __shfl_xor(l, 2, 16);
            l += __shfl_xor(l, 4, 16);
            l += __shfl_xor(l, 8, 16);
            rl[r] = 1.0f / l;
        }
#pragma unroll
        for (int c = 0; c < 8; ++c)
#pragma unroll
            for (int r = 0; r < 4; ++r)
                out[(size_t)(q0w + quad * 4 + r) * DM + h * HD + c * 16 + l15] =
                    (bf16)(o[c][r] * rl[r]);
    }
}

__global__ __launch_bounds__(512) void k_gemm_ksplit(const bf16* __restrict__ A,
                                                     const bf16* __restrict__ Bt,
                                                     float* __restrict__ C) {
    __shared__ __align__(16) char smem[65536];
    const int t = threadIdx.x;
    const int tg = t & 255;
    const int gk = t >> 8;
    const int lane = t & 63;
    const int wl = (t >> 6) & 3;
    const int wr = (wl >> 1) * 64, wc = (wl & 1) * 64;
    const int l15 = lane & 15, quad = lane >> 4;
    const int orig = blockIdx.y * 16 + blockIdx.x;
    const int swz = (orig & 7) * 32 + (orig >> 3);
    const size_t bm = (size_t)(swz / 16) * 128, bn = (size_t)(swz % 16) * 128;
    bf16* Asg = (bf16*)(smem) + gk * 8192;
    bf16* Bsg = (bf16*)(smem + 32768) + gk * 8192;

    f32x4 acc[4][4];
#pragma unroll
    for (int i = 0; i < 4; ++i)
#pragma unroll
        for (int j = 0; j < 4; ++j) acc[i][j] = (f32x4){0.f, 0.f, 0.f, 0.f};

    const int k0 = gk * 1024;
    for (int kt = k0; kt < k0 + 1024; kt += 64) {
#pragma unroll
        for (int j = 0; j < 4; ++j) {
            int c = j * 256 + tg;
            int row = c >> 3, g8 = ((c & 7) ^ (row & 7)) * 8;
            async16(&A[(bm + row) * DM + kt + g8], &Asg[c * 8]);
        }
#pragma unroll
        for (int j = 0; j < 4; ++j) {
            int c = j * 256 + tg;
            int row = c >> 3, g8 = ((c & 7) ^ (row & 7)) * 8;
            async16(&Bt[(bn + row) * DM + kt + g8], &Bsg[c * 8]);
        }
        __syncthreads();
#pragma unroll
        for (int kh = 0; kh < 2; ++kh) {
            bf16x8 af[4], bfm[4];
#pragma unroll
            for (int mi = 0; mi < 4; ++mi)
                af[mi] = *(const bf16x8*)&Asg[sw_idx64(wr + mi * 16 + l15, kh * 4 + quad)];
#pragma unroll
            for (int ni = 0; ni < 4; ++ni)
                bfm[ni] = *(const bf16x8*)&Bsg[sw_idx64(wc + ni * 16 + l15, kh * 4 + quad)];
#pragma unroll
            for (int mi = 0; mi < 4; ++mi)
#pragma unroll
                for (int ni = 0; ni < 4; ++ni)
                    acc[mi][ni] = __builtin_amdgcn_mfma_f32_16x16x32_bf16(
                        af[mi], bfm[ni], acc[mi][ni], 0, 0, 0);
        }
        __syncthreads();
    }
    float* oX = (float*)smem;
    if (gk == 1) {
#pragma unroll
        for (int mi = 0; mi < 4; ++mi)
#pragma unroll
            for (int ni = 0; ni < 4; ++ni)
#pragma unroll
                for (int r = 0; r < 4; ++r)
                    oX[(wr + mi * 16 + quad * 4 + r) * 128 + wc + ni * 16 + l15] =
                        acc[mi][ni][r];
    }
    __syncthreads();
    if (gk == 0) {
#pragma unroll
        for (int mi = 0; mi < 4; ++mi)
#pragma unroll
            for (int ni = 0; ni < 4; ++ni)
#pragma unroll
                for (int r = 0; r < 4; ++r) {
                    int row = wr + mi * 16 + quad * 4 + r;
                    int col = wc + ni * 16 + l15;
                    C[(bm + row) * (size_t)DM + bn + col] =
                        acc[mi][ni][r] + oX[row * 128 + col];
                }
    }
}

extern "C" void kernel_launch(void* const* d_in, const int* in_sizes, int n_in,
                              void* d_out, int out_size, void* d_ws, size_t ws_size,
                              hipStream_t stream) {
    const float* x  = (const float*)d_in[0];
    const float* fc = (const float*)d_in[1];
    const float* fs = (const float*)d_in[2];
    // d_in[3] = mask (unused; causal mask applied analytically)
    const float* wq = (const float*)d_in[4];
    const float* wk = (const float*)d_in[5];
    const float* wv = (const float*)d_in[6];
    const float* wo = (const float*)d_in[7];
    float* out = (float*)d_out;

    char* ws = (char*)d_ws;
    bf16* xb  = (bf16*)(ws);                          //  8MB, reused as attn_out
    bf16* wT  = (bf16*)(ws + (size_t)(8u  << 20));    // 24MB  (wq^T|wk^T|wv^T)
    bf16* woT = (bf16*)(ws + (size_t)(32u << 20));    //  8MB
    bf16* qkv = (bf16*)(ws + (size_t)(40u << 20));    // 24MB  [seq][6144]
    bf16* vT  = (bf16*)(ws + (size_t)(64u << 20));    //  8MB  [c][seq]

    k_prep<<<dim3(32, 32, 5), 256, 0, stream>>>(wq, wk, wv, wo, wT, woT, x, xb);
    k_gemm_bt<bf16, 128><<<dim3(48, 16), 256, 0, stream>>>(xb, wT, qkv, SEQ, QKV_N, DM);

    // cooperative fusion of rope_vt -> flash -> out-proj (saves 2 launch gaps)
    bf16* qkv_a = qkv; bf16* vT_a = vT; const float* fc_a = fc; const float* fs_a = fs;
    bf16* xb_a = xb; const bf16* woT_a = woT; float* out_a = out;
    void* args[] = {&qkv_a, &vT_a, &fc_a, &fs_a, &xb_a, &woT_a, &out_a};
    hipError_t ce = hipLaunchCooperativeKernel((const void*)k_mega, dim3(512),
                                               dim3(512), args, 0, stream);
    if (ce != hipSuccess) {                           // fallback: r13 path
        k_rope_vt<<<3072, 256, 0, stream>>>(qkv, fc, fs, vT);
        k_flash<<<512, 512, 0, stream>>>(qkv, vT, fc, fs, xb);
        k_gemm_ksplit<<<dim3(16, 16), 512, 0, stream>>>(xb, woT, out);
    }
}

// Round 15
// 277.939 us; speedup vs baseline: 1.4107x; 1.4107x over previous
//
#include <hip/hip_runtime.h>
#include <hip/hip_bf16.h>
#include <math.h>

#define SEQ 2048
#define DM 2048
#define NH 16
#define HD 128
#define QKV_N 6144

typedef __bf16 bf16;
typedef __bf16 bf16x8 __attribute__((ext_vector_type(8)));
typedef __bf16 bf16x4v __attribute__((ext_vector_type(4)));
typedef __bf16 bf16x2v __attribute__((ext_vector_type(2)));
typedef float f32x4 __attribute__((ext_vector_type(4)));

// 64-elem-row swizzle (8 chunk slots, 128B row = full bank revolution)
__device__ inline int sw_idx64(int row, int chunk) {
    return (row * 8 + (chunk ^ (row & 7))) * 8;
}
// 128-elem-row swizzle (16 chunk slots, 256B row)
__device__ inline int sw_idx128(int row, int chunk) {
    return (row * 16 + (chunk ^ (row & 15))) * 8;
}
// 32-elem-row swizzle (4 chunk slots, 64B row) -- per-wave P slices
__device__ inline int sw_idx32(int row, int chunk) {
    return (row * 4 + (chunk ^ (row & 3))) * 8;
}

__device__ inline void async16(const void* g, void* l) {
    __builtin_amdgcn_global_load_lds((const __attribute__((address_space(1))) void*)g,
                                     (__attribute__((address_space(3))) void*)l, 16, 0, 0);
}

// ---- weight transposes (z<4, 64x64 tiles, float4 loads) + x convert (z=4) --
__global__ __launch_bounds__(256) void k_prep(const float* __restrict__ wq,
                                              const float* __restrict__ wk,
                                              const float* __restrict__ wv,
                                              const float* __restrict__ wo,
                                              bf16* __restrict__ wT, bf16* __restrict__ woT,
                                              const float* __restrict__ x,
                                              bf16* __restrict__ xb) {
    const int z = blockIdx.z;
    const int t = threadIdx.x;
    if (z == 4) {                                    // x convert: 1M float4s
        int bid = blockIdx.y * 32 + blockIdx.x;      // 0..1023
#pragma unroll
        for (int j = 0; j < 4; ++j) {
            int i = bid * 1024 + j * 256 + t;
            float4 v = ((const float4*)x)[i];
            bf16x4v o;
            o.x = (bf16)v.x; o.y = (bf16)v.y; o.z = (bf16)v.z; o.w = (bf16)v.w;
            ((bf16x4v*)xb)[i] = o;
        }
        return;
    }
    __shared__ bf16 tile[64][66];
    const float* src = (z == 0) ? wq : (z == 1) ? wk : (z == 2) ? wv : wo;
    bf16* dst = (z < 3) ? (wT + (size_t)z * DM * DM) : woT;
    const int bx = blockIdx.x * 64, by = blockIdx.y * 64;
#pragma unroll
    for (int j = 0; j < 4; ++j) {
        int idx = j * 256 + t;                       // 0..1023
        int r = idx >> 4, cg = idx & 15;
        float4 v = *(const float4*)&src[(size_t)(by + r) * DM + bx + cg * 4];
        bf16x4v o;
        o.x = (bf16)v.x; o.y = (bf16)v.y; o.z = (bf16)v.z; o.w = (bf16)v.w;
        *(bf16x4v*)&tile[r][cg * 4] = o;
    }
    __syncthreads();
#pragma unroll
    for (int j = 0; j < 4; ++j) {
        int idx = j * 256 + t;
        int r = idx >> 4, cg = idx & 15;
        bf16x4v o;
        o.x = tile[cg * 4 + 0][r];
        o.y = tile[cg * 4 + 1][r];
        o.z = tile[cg * 4 + 2][r];
        o.w = tile[cg * 4 + 3][r];
        *(bf16x4v*)&dst[(size_t)(bx + r) * DM + by + cg * 4] = o;
    }
}

// ---- fused: V transpose (blocks 0..1023) + K-only RoPE (blocks 1024..3071) -
__global__ __launch_bounds__(256) void k_rope_vt(bf16* __restrict__ qkv,
                                                 const float* __restrict__ cosT,
                                                 const float* __restrict__ sinT,
                                                 bf16* __restrict__ vT) {
    const int t = threadIdx.x;
    if (blockIdx.x >= 1024) {
        // K RoPE: 512K groups of 8 channels (4 rot-pairs), bf16x8 vectorized
        int g = (blockIdx.x - 1024) * 256 + t;       // 0..524287
        int s = g >> 8;                              // 256 groups per row
        int cg = g & 255;
        int h = cg >> 4, w8 = cg & 15;
        size_t base = (size_t)s * QKV_N + DM + h * HD + w8 * 8;
        float4 cv = *(const float4*)&cosT[s * 64 + w8 * 4];
        float4 sv = *(const float4*)&sinT[s * 64 + w8 * 4];
        float cc[4] = {cv.x, cv.y, cv.z, cv.w};
        float ss[4] = {sv.x, sv.y, sv.z, sv.w};
        bf16x8 k = *(bf16x8*)&qkv[base];
        bf16x8 o;
#pragma unroll
        for (int p = 0; p < 4; ++p) {
            float re = (float)k[2 * p], im = (float)k[2 * p + 1];
            o[2 * p]     = (bf16)(re * cc[p] - im * ss[p]);
            o[2 * p + 1] = (bf16)(re * ss[p] + im * cc[p]);
        }
        *(bf16x8*)&qkv[base] = o;
        return;
    }
    // V transpose: vT[c][s] = qkv[s][2*DM + c], 64x64 tiles
    __shared__ bf16 tile[64][66];
    const int bx = (blockIdx.x & 31) * 64, by = (blockIdx.x >> 5) * 64;
#pragma unroll
    for (int j = 0; j < 4; ++j) {
        int idx = j * 256 + t;
        int r = idx >> 4, cg = idx & 15;             // r: seq-row, cg: channel/4
        *(bf16x4v*)&tile[r][cg * 4] =
            *(const bf16x4v*)&qkv[(size_t)(by + r) * QKV_N + 2 * DM + bx + cg * 4];
    }
    __syncthreads();
#pragma unroll
    for (int j = 0; j < 4; ++j) {
        int idx = j * 256 + t;
        int r = idx >> 4, cg = idx & 15;             // r: channel-row, cg: seq/4
        bf16x4v o;
        o.x = tile[cg * 4 + 0][r];
        o.y = tile[cg * 4 + 1][r];
        o.z = tile[cg * 4 + 2][r];
        o.w = tile[cg * 4 + 3][r];
        *(bf16x4v*)&vT[(size_t)(bx + r) * SEQ + by + cg * 4] = o;
    }
}

// ---- shared 128xBN GEMM body: C[.][N] = A[M][K] * Bt[N][K]^T --------------
template <typename OutT, int BN>
__device__ __forceinline__ void gemm_body(const bf16* __restrict__ A,
                                          const bf16* __restrict__ Bt,
                                          OutT* __restrict__ C,
                                          int N, int K, size_t bm, size_t bn,
                                          bf16* As, bf16* Bs) {
    constexpr int NI = BN / 32;
    const int t = threadIdx.x;
    const int lane = t & 63;
    const int w = t >> 6;
    const int wr = (w >> 1) * 64, wc = (w & 1) * (BN / 2);
    const int l15 = lane & 15, quad = lane >> 4;
    f32x4 acc[4][NI];
#pragma unroll
    for (int i = 0; i < 4; ++i)
#pragma unroll
        for (int j = 0; j < NI; ++j) acc[i][j] = (f32x4){0.f, 0.f, 0.f, 0.f};

    for (int kt = 0; kt < K; kt += 64) {
#pragma unroll
        for (int j = 0; j < 4; ++j) {
            int c = j * 256 + t;
            int row = c >> 3, g = ((c & 7) ^ (row & 7)) * 8;
            async16(&A[(bm + row) * K + kt + g], &As[c * 8]);
        }
#pragma unroll
        for (int j = 0; j < NI; ++j) {
            int c = j * 256 + t;
            int row = c >> 3, g = ((c & 7) ^ (row & 7)) * 8;
            async16(&Bt[(bn + row) * K + kt + g], &Bs[c * 8]);
        }
        __syncthreads();
#pragma unroll
        for (int kh = 0; kh < 2; ++kh) {
            bf16x8 af[4], bfm[NI];
#pragma unroll
            for (int mi = 0; mi < 4; ++mi)
                af[mi] = *(const bf16x8*)&As[sw_idx64(wr + mi * 16 + l15, kh * 4 + quad)];
#pragma unroll
            for (int ni = 0; ni < NI; ++ni)
                bfm[ni] = *(const bf16x8*)&Bs[sw_idx64(wc + ni * 16 + l15, kh * 4 + quad)];
#pragma unroll
            for (int mi = 0; mi < 4; ++mi)
#pragma unroll
                for (int ni = 0; ni < NI; ++ni)
                    acc[mi][ni] = __builtin_amdgcn_mfma_f32_16x16x32_bf16(
                        af[mi], bfm[ni], acc[mi][ni], 0, 0, 0);
        }
        __syncthreads();
    }
#pragma unroll
    for (int mi = 0; mi < 4; ++mi)
#pragma unroll
        for (int ni = 0; ni < NI; ++ni)
#pragma unroll
            for (int r = 0; r < 4; ++r) {
                size_t row = bm + wr + mi * 16 + quad * 4 + r;
                size_t col = bn + wc + ni * 16 + l15;
                C[row * (size_t)N + col] = (OutT)acc[mi][ni][r];
            }
}

// Plain blockIdx mapping (XCD swizzle harmful here: r12 measured 2.7x FETCH,
// +6us -- localizing the 8MB A made each XCD sweep all of the 24MB B,
// thrashing its 4MB L2).
template <typename OutT, int BN>
__global__ __launch_bounds__(256) void k_gemm_bt(const bf16* __restrict__ A,
                                                 const bf16* __restrict__ Bt,
                                                 OutT* __restrict__ C,
                                                 int M, int N, int K) {
    __shared__ bf16 As[128 * 64];
    __shared__ bf16 Bs[BN * 64];
    size_t bm = (size_t)blockIdx.y * 128, bn = (size_t)blockIdx.x * BN;
    gemm_body<OutT, BN>(A, Bt, C, N, K, bm, bn, As, Bs);
}

// ---- out-proj GEMM, 128x128 tile, K-split across 2 wave-groups ------------
// grid(16,16) = 256 blocks, 512 threads = 2 groups x 4 waves; group g runs
// K-half g with its own 16KB As/Bs; merge via LDS at the end (no HBM
// partials).  XCD swizzle KEPT (r12 A/B attribution: ~-6us): 2MB A-panel per
// XCD fits its L2; B re-use handled by L3.
__global__ __launch_bounds__(512) void k_gemm_ksplit(const bf16* __restrict__ A,
                                                     const bf16* __restrict__ Bt,
                                                     float* __restrict__ C) {
    __shared__ __align__(16) char smem[65536];
    const int t = threadIdx.x;
    const int tg = t & 255;                          // thread within group
    const int gk = t >> 8;                           // K-half 0/1
    const int lane = t & 63;
    const int wl = (t >> 6) & 3;                     // wave within group
    const int wr = (wl >> 1) * 64, wc = (wl & 1) * 64;
    const int l15 = lane & 15, quad = lane >> 4;
    // XCD swizzle (256 blocks, cpx=32): each XCD gets 2 contiguous M-rows
    const int orig = blockIdx.y * 16 + blockIdx.x;
    const int swz = (orig & 7) * 32 + (orig >> 3);
    const size_t bm = (size_t)(swz / 16) * 128, bn = (size_t)(swz % 16) * 128;
    bf16* Asg = (bf16*)(smem) + gk * 8192;
    bf16* Bsg = (bf16*)(smem + 32768) + gk * 8192;

    f32x4 acc[4][4];
#pragma unroll
    for (int i = 0; i < 4; ++i)
#pragma unroll
        for (int j = 0; j < 4; ++j) acc[i][j] = (f32x4){0.f, 0.f, 0.f, 0.f};

    const int k0 = gk * 1024;
    for (int kt = k0; kt < k0 + 1024; kt += 64) {
#pragma unroll
        for (int j = 0; j < 4; ++j) {
            int c = j * 256 + tg;
            int row = c >> 3, g8 = ((c & 7) ^ (row & 7)) * 8;
            async16(&A[(bm + row) * DM + kt + g8], &Asg[c * 8]);
        }
#pragma unroll
        for (int j = 0; j < 4; ++j) {
            int c = j * 256 + tg;
            int row = c >> 3, g8 = ((c & 7) ^ (row & 7)) * 8;
            async16(&Bt[(bn + row) * DM + kt + g8], &Bsg[c * 8]);
        }
        __syncthreads();
#pragma unroll
        for (int kh = 0; kh < 2; ++kh) {
            bf16x8 af[4], bfm[4];
#pragma unroll
            for (int mi = 0; mi < 4; ++mi)
                af[mi] = *(const bf16x8*)&Asg[sw_idx64(wr + mi * 16 + l15, kh * 4 + quad)];
#pragma unroll
            for (int ni = 0; ni < 4; ++ni)
                bfm[ni] = *(const bf16x8*)&Bsg[sw_idx64(wc + ni * 16 + l15, kh * 4 + quad)];
#pragma unroll
            for (int mi = 0; mi < 4; ++mi)
#pragma unroll
                for (int ni = 0; ni < 4; ++ni)
                    acc[mi][ni] = __builtin_amdgcn_mfma_f32_16x16x32_bf16(
                        af[mi], bfm[ni], acc[mi][ni], 0, 0, 0);
        }
        __syncthreads();
    }
    // ---- merge K-halves via LDS (staging buffers are dead now) ----
    float* oX = (float*)smem;                        // 128x128 fp32 = 64KB
    if (gk == 1) {
#pragma unroll
        for (int mi = 0; mi < 4; ++mi)
#pragma unroll
            for (int ni = 0; ni < 4; ++ni)
#pragma unroll
                for (int r = 0; r < 4; ++r)
                    oX[(wr + mi * 16 + quad * 4 + r) * 128 + wc + ni * 16 + l15] =
                        acc[mi][ni][r];
    }
    __syncthreads();
    if (gk == 0) {
#pragma unroll
        for (int mi = 0; mi < 4; ++mi)
#pragma unroll
            for (int ni = 0; ni < 4; ++ni)
#pragma unroll
                for (int r = 0; r < 4; ++r) {
                    int row = wr + mi * 16 + quad * 4 + r;
                    int col = wc + ni * 16 + l15;
                    C[(bm + row) * (size_t)DM + bn + col] =
                        acc[mi][ni][r] + oX[row * 128 + col];
                }
    }
}

// ---- causal flash attention: 64-q-row blocks, key-split across wave pairs --
// (round-8 structure: best of 5 measured variants, ~54.6us)  512 blocks = 32
// q-tiles x 16 heads, 512 threads = 8 waves = 4 q-strips x 2 key-halves.  16
// waves/CU (2 blocks x 8 waves) is the empirically dominant factor (8-wave/CU
// variants were ~15% slower regardless of LDS traffic) -- latency-bound,
// lives on TLP.  Natural VGPR (~60-76) must NOT be capped: r14's 64-cap
// caused scratch spills (+33MB WRITE_SIZE, 3x slowdown).  Wave (wl,g): QK for
// key sub-tiles {2g,2g+1}, softmax for its 8 scores, PV with its private
// 16x32 P slice.  Partials combined at end via LDS (Ks reuse).  Pairing:
// blocks b,b+256 (same CU, same head) qb sums to 31.  Split waits: vmcnt(6)
// tile-top (cur K), vmcnt(4) after softmax (cur V).
__global__ __launch_bounds__(512) void k_flash(const bf16* __restrict__ qkv,
                                               const bf16* __restrict__ vT,
                                               const float* __restrict__ cosT,
                                               const float* __restrict__ sinT,
                                               bf16* __restrict__ out) {
    __shared__ bf16 Ks[2][64 * 128];                 // [key][d] swizzled (32KB)
    __shared__ bf16 Vs[2][128 * 64];                 // [ch][key] swizzled (32KB)
    __shared__ bf16 Pl[8][16 * 32];                  // per-wave P slice (8KB)
    const int t = threadIdx.x;
    const int lane = t & 63;
    const int w = t >> 6;                            // 0..7
    const int wl = w & 3;                            // q-strip
    const int g = w >> 2;                            // key-half 0/1
    const int l15 = lane & 15, quad = lane >> 4;
    const int b = blockIdx.x;                        // 0..511
    const int hc = b & 15;
    const int h = (hc & 7) * 2 + (hc >> 3);
    const int qb = (b < 256) ? (31 - (b >> 4)) : ((b >> 4) - 16);  // pair sums 31
    const int q0w = qb * 64 + wl * 16;
    const float sc2 = 0.08838834764831845f * 1.4426950408889634f;  // /sqrt(128)*log2e

    const size_t qrow = (size_t)(q0w + l15) * QKV_N + h * HD;
    bf16x8 aq[4];
#pragma unroll
    for (int u = 0; u < 4; ++u)
        aq[u] = *(const bf16x8*)&qkv[qrow + u * 32 + quad * 8];
    // in-register Q RoPE: lane's 8 consecutive channels = 4 complete rot-pairs
#pragma unroll
    for (int u = 0; u < 4; ++u) {
        float4 cv = *(const float4*)&cosT[(q0w + l15) * 64 + u * 16 + quad * 4];
        float4 sv = *(const float4*)&sinT[(q0w + l15) * 64 + u * 16 + quad * 4];
        float cc[4] = {cv.x, cv.y, cv.z, cv.w};
        float ss[4] = {sv.x, sv.y, sv.z, sv.w};
        bf16x8 q = aq[u], rq;
#pragma unroll
        for (int pp = 0; pp < 4; ++pp) {
            float re = (float)q[2 * pp], im = (float)q[2 * pp + 1];
            rq[2 * pp]     = (bf16)(re * cc[pp] - im * ss[pp]);
            rq[2 * pp + 1] = (bf16)(re * ss[pp] + im * cc[pp]);
        }
        aq[u] = rq;
    }

    f32x4 o[8];
#pragma unroll
    for (int c = 0; c < 8; ++c) o[c] = (f32x4){0.f, 0.f, 0.f, 0.f};
    float l_r[4] = {0.f, 0.f, 0.f, 0.f};

    // staging: 1024 K-chunks + 1024 V-chunks per tile over 512 threads = 2+2
    int krow[2], kg[2], vrow[2], vg[2];
#pragma unroll
    for (int j = 0; j < 2; ++j) {
        int c2 = j * 512 + t;
        krow[j] = c2 >> 4; kg[j] = ((c2 & 15) ^ (krow[j] & 15)) * 8;  // 16 chunks/row
        vrow[j] = c2 >> 3; vg[j] = ((c2 & 7) ^ (vrow[j] & 7)) * 8;    //  8 chunks/row
    }
    // issue order matters for split vmcnt counting: K first, then V.
    auto stage = [&](int buf, int kt2) {
        const int kb2 = kt2 * 64;
#pragma unroll
        for (int j = 0; j < 2; ++j)
            async16(&qkv[(size_t)(kb2 + krow[j]) * QKV_N + DM + h * HD + kg[j]],
                    &Ks[buf][(j * 512 + t) * 8]);
#pragma unroll
        for (int j = 0; j < 2; ++j)
            async16(&vT[(size_t)(h * HD + vrow[j]) * SEQ + kb2 + vg[j]],
                    &Vs[buf][(j * 512 + t) * 8]);
    };

    const int nT = qb + 1;
    stage(0, 0);
    for (int kt = 0; kt < nT; ++kt) {
        const int cb = kt & 1;
        const int kbase = kt * 64;
        const bool pre = (kt + 1 < nT);
        if (pre) {
            stage(cb ^ 1, kt + 1);                   // prefetch next tile
            asm volatile("s_waitcnt vmcnt(6)" ::: "memory");   // cur K done
        } else {
            asm volatile("s_waitcnt vmcnt(2)" ::: "memory");
        }
        __builtin_amdgcn_s_barrier();                // K staged for all
        asm volatile("" ::: "memory");

        // ---- QK^T: this wave's 2 key sub-tiles x 4 d-chunks ----
        f32x4 s4[2];
        __builtin_amdgcn_s_setprio(1);
#pragma unroll
        for (int sl = 0; sl < 2; ++sl) {
            const int sub = 2 * g + sl;
            f32x4 z = (f32x4){0.f, 0.f, 0.f, 0.f};
#pragma unroll
            for (int u = 0; u < 4; ++u) {
                bf16x8 kv = *(const bf16x8*)&Ks[cb][sw_idx128(sub * 16 + l15, u * 4 + quad)];
                z = __builtin_amdgcn_mfma_f32_16x16x32_bf16(aq[u], kv, z, 0, 0, 0);
            }
            s4[sl] = z;
        }
        __builtin_amdgcn_s_setprio(0);
        const bool masked = (kt == qb);
#pragma unroll
        for (int sl = 0; sl < 2; ++sl) {
            const int sub = 2 * g + sl;
#pragma unroll
            for (int r = 0; r < 4; ++r) {
                float pv = __builtin_amdgcn_exp2f(s4[sl][r] * sc2);
                if (masked)
                    pv = (kbase + sub * 16 + l15 <= q0w + quad * 4 + r) ? pv : 0.f;
                l_r[r] += pv;
                int rowp = quad * 4 + r;
                int lc = sl * 16 + l15;              // local key col 0..31
                Pl[w][(rowp * 4 + ((lc >> 3) ^ (rowp & 3))) * 8 + (lc & 7)] = (bf16)pv;
            }
        }
        // V stall hidden under QK^T+softmax: retire cur V
        if (pre) asm volatile("s_waitcnt vmcnt(4)" ::: "memory");
        else     asm volatile("s_waitcnt vmcnt(0)" ::: "memory");
        __builtin_amdgcn_s_barrier();                // V staged for all
        __asm__ __volatile__("s_waitcnt lgkmcnt(0)" ::: "memory");  // own P visible
        // pf: A-frag over this wave's 32 keys: row=l15, k=quad*8..quad*8+7
        bf16x8 pf = *(const bf16x8*)&Pl[w][sw_idx32(l15, quad)];
        __builtin_amdgcn_s_setprio(1);
#pragma unroll
        for (int c = 0; c < 8; ++c) {
            bf16x8 vb = *(const bf16x8*)&Vs[cb][sw_idx64(c * 16 + l15, g * 4 + quad)];
            o[c] = __builtin_amdgcn_mfma_f32_16x16x32_bf16(pf, vb, o[c], 0, 0, 0);
        }
        __builtin_amdgcn_s_setprio(0);
        asm volatile("" ::: "memory");
        __builtin_amdgcn_s_barrier();                // all waves done with buf cb
        asm volatile("" ::: "memory");
    }

    // ---- combine key-halves: g=1 pushes partials via LDS (Ks reuse) --------
    __syncthreads();                                 // main loop fully done
    float* oxch = (float*)&Ks[0][0];                 // 32KB: 256 thr x 32 f32
    float* lxch = (float*)&Pl[0][0];                 // 4KB:  256 thr x 4 f32
    const int tp = t & 255;
    if (g == 1) {
#pragma unroll
        for (int c = 0; c < 8; ++c)
            *(f32x4*)&oxch[tp * 32 + c * 4] = o[c];
#pragma unroll
        for (int r = 0; r < 4; ++r) lxch[tp * 4 + r] = l_r[r];
    }
    __syncthreads();
    if (g == 0) {
#pragma unroll
        for (int c = 0; c < 8; ++c) {
            f32x4 v = *(const f32x4*)&oxch[tp * 32 + c * 4];
            o[c] += v;
        }
#pragma unroll
        for (int r = 0; r < 4; ++r) l_r[r] += lxch[tp * 4 + r];
        float rl[4];
#pragma unroll
        for (int r = 0; r < 4; ++r) {
            float l = l_r[r];
            l += __shfl_xor(l, 1, 16);
            l += __shfl_xor(l, 2, 16);
            l += __shfl_xor(l, 4, 16);
            l += __shfl_xor(l, 8, 16);
            rl[r] = 1.0f / l;
        }
#pragma unroll
        for (int c = 0; c < 8; ++c)
#pragma unroll
            for (int r = 0; r < 4; ++r)
                out[(size_t)(q0w + quad * 4 + r) * DM + h * HD + c * 16 + l15] =
                    (bf16)(o[c][r] * rl[r]);
    }
}

extern "C" void kernel_launch(void* const* d_in, const int* in_sizes, int n_in,
                              void* d_out, int out_size, void* d_ws, size_t ws_size,
                              hipStream_t stream) {
    const float* x  = (const float*)d_in[0];
    const float* fc = (const float*)d_in[1];
    const float* fs = (const float*)d_in[2];
    // d_in[3] = mask (unused; causal mask applied analytically)
    const float* wq = (const float*)d_in[4];
    const float* wk = (const float*)d_in[5];
    const float* wv = (const float*)d_in[6];
    const float* wo = (const float*)d_in[7];
    float* out = (float*)d_out;

    char* ws = (char*)d_ws;
    bf16* xb  = (bf16*)(ws);                          //  8MB, reused as attn_out
    bf16* wT  = (bf16*)(ws + (size_t)(8u  << 20));    // 24MB  (wq^T|wk^T|wv^T)
    bf16* woT = (bf16*)(ws + (size_t)(32u << 20));    //  8MB
    bf16* qkv = (bf16*)(ws + (size_t)(40u << 20));    // 24MB  [seq][6144]
    bf16* vT  = (bf16*)(ws + (size_t)(64u << 20));    //  8MB  [c][seq]

    k_prep<<<dim3(32, 32, 5), 256, 0, stream>>>(wq, wk, wv, wo, wT, woT, x, xb);
    k_gemm_bt<bf16, 128><<<dim3(48, 16), 256, 0, stream>>>(xb, wT, qkv, SEQ, QKV_N, DM);
    k_rope_vt<<<3072, 256, 0, stream>>>(qkv, fc, fs, vT);
    k_flash<<<512, 512, 0, stream>>>(qkv, vT, fc, fs, xb);
    k_gemm_ksplit<<<dim3(16, 16), 512, 0, stream>>>(xb, woT, out);
}